// Round 1
// baseline (172.566 us; speedup 1.0000x reference)
//
#include <hip/hip_runtime.h>
#include <hip/hip_bf16.h>
#include <stdint.h>

// KAN layer fused kernel, MI355X (gfx950) — barrier-free wave-strip version.
// out[M=65536, N=256] (fp32) = A[M, K=256] @ W^T, where
//   A[m,k] = c0[k]*B0(tanh(x[m,k])) + c1[k]*B1(tanh(x[m,k]))  (on the fly -> bf16)
//   W = outer_coeffs [N,K] fp32 -> bf16 (conv_w into d_ws)
//
// V2 structure: each wave owns a 16-row x 256-col output strip.
//  - A fragments computed entirely in-register (each lane's 8 k-values are its own
//    x elements) -> no LDS A tile, no cross-thread sharing, no redundancy.
//  - B fragments loaded global->register (W is L1/L2-resident; lanes of the 4 quads
//    cover 64 B contiguous per row -> fully coalesced).
//  - NO per-K-step __syncthreads, no vmcnt(0) barrier drains. Latency hidden by
//    issuing 16 B-loads + next-iter x prefetch before the ~400-cycle spline VALU block.

typedef __attribute__((ext_vector_type(8))) short short8;   // 8 bf16 = 4 VGPR (MFMA A/B frag)
typedef __attribute__((ext_vector_type(4))) float f32x4;    // MFMA C/D frag

__device__ __forceinline__ uint16_t f2bf(float f) {
    union { float f; uint32_t u; } v; v.f = f;
    uint32_t r = v.u + 0x7FFFu + ((v.u >> 16) & 1u);  // RNE
    return (uint16_t)(r >> 16);
}

// Pack 2 floats -> 2 bf16 (RNE) in one v_cvt_pk_bf16_f32 (compiler-emitted; m240)
__device__ __forceinline__ uint32_t pack_bf2(float lo, float hi) {
    __hip_bfloat162 h = __float22bfloat162_rn(make_float2(lo, hi));
    union { __hip_bfloat162 h; uint32_t u; } v; v.h = h;
    return v.u;
}

__device__ __forceinline__ float cube_relu(float v) {
    float m = fmaxf(v, 0.0f);
    return m * m * m;
}

__device__ __forceinline__ float inner_eval(float xx, float c0, float c1) {
    // tanh via exp: tanh(x) = 1 - 2/(e^{2x}+1); saturates correctly at +/-inf
    float e  = __expf(2.0f * xx);
    float t  = 1.0f - 2.0f * __builtin_amdgcn_rcpf(e + 1.0f);
    float u  = (t + 1.0f) * 3.5f;          // in [0,7]
    float w0 = cube_relu(u);
    float w1 = cube_relu(u - 1.0f);
    float w2 = cube_relu(u - 2.0f);
    float w3 = cube_relu(u - 3.0f);
    float w4 = cube_relu(u - 4.0f);
    float w5 = cube_relu(u - 5.0f);
    float B0 = w0 - 4.0f*w1 + 6.0f*w2 - 4.0f*w3 + w4;
    float B1 = w1 - 4.0f*w2 + 6.0f*w3 - 4.0f*w4 + w5;
    return (c0 * B0 + c1 * B1) * (1.0f / 6.0f);
}

// W fp32 -> bf16, 65536 elems, 4/thread
__global__ void conv_w(const float4* __restrict__ wf, uint2* __restrict__ o) {
    const int i = blockIdx.x * blockDim.x + threadIdx.x;  // 0..16383
    const float4 v = wf[i];
    uint2 r;
    r.x = (uint32_t)f2bf(v.x) | ((uint32_t)f2bf(v.y) << 16);
    r.y = (uint32_t)f2bf(v.z) | ((uint32_t)f2bf(v.w) << 16);
    o[i] = r;
}

// Block: 256 threads = 4 independent waves. Wave w owns rows [bid*64 + w*16, +16),
// all 256 output cols (16 n-tiles of 16x16x32 MFMA), K loop of 8 x BK=32.
// MFMA operand mapping (verified by prior kernel): lane=(mrow=lane&15, quad=lane>>4);
//   A frag: A[m=mrow][k=quad*8..+8]; B frag: W[n=mrow][k=quad*8..+8];
//   C/D: col=mrow (pairs with B tile), row=quad*4+r (pairs with A rows).
__global__ void __launch_bounds__(256) kan_fused(const float* __restrict__ x,
                                                 const float* __restrict__ ic,
                                                 const uint16_t* __restrict__ wb,
                                                 float* __restrict__ out)
{
    __shared__ __align__(16) float2 C2[256];   // (c0,c1) per channel — only LDS use

    const int t    = threadIdx.x;
    const int lane = t & 63;
    const int w    = t >> 6;
    const int mrow = lane & 15;
    const int quad = lane >> 4;
    const int m    = blockIdx.x * 64 + w * 16 + mrow;   // this lane's A row

    C2[t] = make_float2(ic[t * 5 + 0], ic[t * 5 + 1]);
    __syncthreads();   // the only barrier in the kernel

    f32x4 acc[16];
    #pragma unroll
    for (int j = 0; j < 16; ++j) acc[j] = (f32x4){0.f, 0.f, 0.f, 0.f};

    const float*    xp = x  + (size_t)m * 256 + quad * 8;   // lane's x: row m, k base quad*8
    const uint16_t* wp = wb + mrow * 256 + quad * 8;        // B frag base: row mrow (n-tile adds j*16 rows)

    // prefetch x for kk=0 (8 floats = this lane's A inputs for the K-step)
    float4 xa = *(const float4*)(xp + 0);
    float4 xb = *(const float4*)(xp + 4);

    #pragma unroll 1
    for (int kk = 0; kk < 8; ++kk) {
        // --- issue all 16 B-fragment loads first (L1/L2-hot; 64B-coalesced) ---
        short8 b[16];
        #pragma unroll
        for (int j = 0; j < 16; ++j)
            b[j] = *(const short8*)(wp + j * 4096 + kk * 32);   // row j*16+mrow, k=kk*32+quad*8

        // --- issue next-iter x prefetch (hides HBM/L3 latency under this iter) ---
        float4 xa_n = xa, xb_n = xb;
        if (kk < 7) {
            xa_n = *(const float4*)(xp + kk * 32 + 32);
            xb_n = *(const float4*)(xp + kk * 32 + 36);
        }

        // --- coeffs for this lane's 8 channels (broadcast-friendly LDS reads) ---
        const int gk = kk * 32 + quad * 8;
        const float4 cA = *(const float4*)(&C2[gk + 0]);   // c0,c1 of gk, gk+1
        const float4 cB = *(const float4*)(&C2[gk + 2]);
        const float4 cC = *(const float4*)(&C2[gk + 4]);
        const float4 cD = *(const float4*)(&C2[gk + 6]);

        // --- spline VALU block (covers the B-load latency) ---
        float v0 = inner_eval(xa.x, cA.x, cA.y);
        float v1 = inner_eval(xa.y, cA.z, cA.w);
        float v2 = inner_eval(xa.z, cB.x, cB.y);
        float v3 = inner_eval(xa.w, cB.z, cB.w);
        float v4 = inner_eval(xb.x, cC.x, cC.y);
        float v5 = inner_eval(xb.y, cC.z, cC.w);
        float v6 = inner_eval(xb.z, cD.x, cD.y);
        float v7 = inner_eval(xb.w, cD.z, cD.w);

        union { short8 v; uint32_t u[4]; } af;
        af.u[0] = pack_bf2(v0, v1);
        af.u[1] = pack_bf2(v2, v3);
        af.u[2] = pack_bf2(v4, v5);
        af.u[3] = pack_bf2(v6, v7);

        // --- MFMA sweep over the 16 n-tiles ---
        #pragma unroll
        for (int j = 0; j < 16; ++j)
            acc[j] = __builtin_amdgcn_mfma_f32_16x16x32_bf16(af.v, b[j], acc[j], 0, 0, 0);

        xa = xa_n; xb = xb_n;
    }

    // --- epilogue: fp32 stores; per inst: 4 quad-rows x 64B contiguous segments ---
    float* op = out + (size_t)(blockIdx.x * 64 + w * 16 + quad * 4) * 256 + mrow;
    #pragma unroll
    for (int j = 0; j < 16; ++j) {
        #pragma unroll
        for (int r = 0; r < 4; ++r)
            op[(size_t)r * 256 + j * 16] = acc[j][r];
    }
}

extern "C" void kernel_launch(void* const* d_in, const int* in_sizes, int n_in,
                              void* d_out, int out_size, void* d_ws, size_t ws_size,
                              hipStream_t stream) {
    const float* x  = (const float*)d_in[0];   // [16,4096,256] fp32
    const float* ic = (const float*)d_in[1];   // [256,5] fp32
    const float* oc = (const float*)d_in[2];   // [256,256] fp32
    uint16_t* wb = (uint16_t*)d_ws;            // 128 KB bf16 copy of W

    conv_w<<<64, 256, 0, stream>>>((const float4*)oc, (uint2*)wb);
    kan_fused<<<1024, 256, 0, stream>>>(x, ic, wb, (float*)d_out);
}

// Round 2
// 130.821 us; speedup vs baseline: 1.3191x; 1.3191x over previous
//
#include <hip/hip_runtime.h>
#include <hip/hip_bf16.h>
#include <stdint.h>

// KAN layer fused kernel, MI355X (gfx950) — V3: whole-W-in-LDS, barrier-free main loop.
// out[M=65536, N=256] (fp32) = A[M, K=256] @ W^T, where
//   A[m,k] = c0[k]*B0(tanh(x[m,k])) + c1[k]*B1(tanh(x[m,k]))  (on the fly -> bf16)
//   W = outer_coeffs [N,K] fp32 -> bf16 (conv_w, SWIZZLED layout, into d_ws)
//
// Lessons encoded:
//  - V1 (58us): LDS B-staging works but 2 barriers/K-step -> vmcnt(0) drains dominate.
//  - V2 (87us): global per-lane B loads fragment into 16x64B segments AND compiler
//    (no min-waves hint) capped VGPR at 96, sinking loads next to MFMAs -> serialized.
//  - V3: stage ALL of W (128KB bf16) into LDS ONCE via global_load_lds (conv_w
//    pre-swizzles so linear DMA + swizzled ds_read agree — both-sides rule), then a
//    ZERO-barrier main loop: A in-register (each lane's 8 k-values are its own x),
//    B via ds_read_b128. 1 block/CU (LDS-limited), launch_bounds(512,2) -> VGPR cap 256
//    so b[16]+acc[16]+prefetch stay live and loads hoist.
//  - XOR swizzle byte^=((row&7)<<4): without it, 16 lanes/quad read rows at 512B
//    stride = same 4-bank group = 16-way conflict (G4 attn case, +89% there).

typedef __attribute__((ext_vector_type(8))) short short8;   // 8 bf16 = 4 VGPR (MFMA A/B frag)
typedef __attribute__((ext_vector_type(4))) float f32x4;    // MFMA C/D frag

__device__ __forceinline__ uint16_t f2bf(float f) {
    union { float f; uint32_t u; } v; v.f = f;
    uint32_t r = v.u + 0x7FFFu + ((v.u >> 16) & 1u);  // RNE
    return (uint16_t)(r >> 16);
}

// Pack 2 floats -> 2 bf16 (RNE) in one v_cvt_pk_bf16_f32 (compiler-emitted)
__device__ __forceinline__ uint32_t pack_bf2(float lo, float hi) {
    __hip_bfloat162 h = __float22bfloat162_rn(make_float2(lo, hi));
    union { __hip_bfloat162 h; uint32_t u; } v; v.h = h;
    return v.u;
}

__device__ __forceinline__ float cube_relu(float v) {
    float m = fmaxf(v, 0.0f);
    return m * m * m;
}

__device__ __forceinline__ float inner_eval(float xx, float c0, float c1) {
    // tanh via exp: tanh(x) = 1 - 2/(e^{2x}+1); saturates correctly at +/-inf
    float e  = __expf(2.0f * xx);
    float t  = 1.0f - 2.0f * __builtin_amdgcn_rcpf(e + 1.0f);
    float u  = (t + 1.0f) * 3.5f;          // in [0,7]
    float w0 = cube_relu(u);
    float w1 = cube_relu(u - 1.0f);
    float w2 = cube_relu(u - 2.0f);
    float w3 = cube_relu(u - 3.0f);
    float w4 = cube_relu(u - 4.0f);
    float w5 = cube_relu(u - 5.0f);
    float B0 = w0 - 4.0f*w1 + 6.0f*w2 - 4.0f*w3 + w4;
    float B1 = w1 - 4.0f*w2 + 6.0f*w3 - 4.0f*w4 + w5;
    return (c0 * B0 + c1 * B1) * (1.0f / 6.0f);
}

__device__ __forceinline__ void load_lds16(const void* g, void* l) {
    __builtin_amdgcn_global_load_lds(
        (const __attribute__((address_space(1))) uint32_t*)g,
        (__attribute__((address_space(3))) uint32_t*)l, 16, 0, 0);
}

// W fp32 -> bf16 into the XOR-SWIZZLED layout kan_fused's ds_reads expect:
//   value W[row][col] lands at byte  row*512 + ((col*2) ^ ((row&7)<<4)).
// Thread i covers floats 4i..4i+3 = one 8-byte bf16 chunk (col*2 is 8-aligned;
// XOR touches bits 4..6 only, so the chunk stays 8-aligned and contiguous).
__global__ void conv_w(const float4* __restrict__ wf, char* __restrict__ o) {
    const int i = blockIdx.x * blockDim.x + threadIdx.x;  // 0..16383
    const float4 v = wf[i];
    uint2 r;
    r.x = (uint32_t)f2bf(v.x) | ((uint32_t)f2bf(v.y) << 16);
    r.y = (uint32_t)f2bf(v.z) | ((uint32_t)f2bf(v.w) << 16);
    const int row = i >> 6;           // 64 threads per 256-float row
    const int cb  = (i & 63) << 3;    // byte col within row, 8-aligned
    *(uint2*)(o + row * 512 + (cb ^ ((row & 7) << 4))) = r;
}

// Block: 512 threads = 8 waves, grid 256 -> exactly 1 block/CU (LDS-limited).
// Wave w handles row strips (s*8+w)*16, s=0..1; all 256 output cols (16 n-tiles).
// MFMA operand mapping (verified V1/V2): lane=(mrow=lane&15, quad=lane>>4);
//   A frag: A[m=mrow][k=quad*8+j]; B frag: W[n=mrow][k=quad*8+j];
//   C/D: col=mrow, row=quad*4+r.
__global__ void __launch_bounds__(512, 2) kan_fused(const float* __restrict__ x,
                                                    const float* __restrict__ ic,
                                                    const char* __restrict__ wb,
                                                    float* __restrict__ out)
{
    __shared__ __align__(16) char Wlds[131072];   // full W, bf16, swizzled
    __shared__ __align__(16) float2 C2[256];      // (c0,c1) per channel

    const int t    = threadIdx.x;
    const int lane = t & 63;
    const int w    = t >> 6;
    const int mrow = lane & 15;
    const int quad = lane >> 4;

    if (t < 256) C2[t] = make_float2(ic[t * 5 + 0], ic[t * 5 + 1]);

    // Early x prefetch for strip 0, kk 0 (in flight during W staging)
    const float* xp0 = x + (size_t)(blockIdx.x * 256 + w * 16 + mrow) * 256 + quad * 8;
    float4 xa = *(const float4*)(xp0);
    float4 xb = *(const float4*)(xp0 + 4);

    // Stage all 128 KB of (pre-swizzled) W linearly: 16 issues x 8 waves x 1 KB.
    #pragma unroll
    for (int it = 0; it < 16; ++it) {
        const int base = ((it * 8 + w) << 10) + lane * 16;
        load_lds16(wb + base, Wlds + base);
    }
    __syncthreads();   // the ONLY barrier: drains vmcnt (W staged) + covers C2

    const int cbase = quad * 16;            // byte col base within a W row
    const int swz   = (mrow & 7) << 4;      // bank-conflict swizzle

    #pragma unroll 1
    for (int s = 0; s < 2; ++s) {
        const int mbase = blockIdx.x * 256 + (s * 8 + w) * 16;
        const float* xp = x + (size_t)(mbase + mrow) * 256 + quad * 8;
        if (s) {  // strip 1: fresh initial prefetch
            xa = *(const float4*)(xp);
            xb = *(const float4*)(xp + 4);
        }

        f32x4 acc[16];
        #pragma unroll
        for (int j = 0; j < 16; ++j) acc[j] = (f32x4){0.f, 0.f, 0.f, 0.f};

        #pragma unroll 1
        for (int kk = 0; kk < 8; ++kk) {
            // --- B frags from LDS (swizzled). Per lane: fixed col word, rows 8KB apart.
            const int cw = (kk * 64 + cbase) ^ swz;
            short8 b[16];
            #pragma unroll
            for (int j = 0; j < 16; ++j)
                b[j] = *(const short8*)(Wlds + (j * 16 + mrow) * 512 + cw);

            // --- next-iter x prefetch (hides HBM/L3 latency under spline VALU) ---
            float4 xa_n = xa, xb_n = xb;
            if (kk < 7) {
                xa_n = *(const float4*)(xp + kk * 32 + 32);
                xb_n = *(const float4*)(xp + kk * 32 + 36);
            }

            // --- coeffs for this lane's 8 channels (LDS broadcast) ---
            const int gk = kk * 32 + quad * 8;
            const float4 cA = *(const float4*)(&C2[gk + 0]);
            const float4 cB = *(const float4*)(&C2[gk + 2]);
            const float4 cC = *(const float4*)(&C2[gk + 4]);
            const float4 cD = *(const float4*)(&C2[gk + 6]);

            // --- spline VALU block ---
            float v0 = inner_eval(xa.x, cA.x, cA.y);
            float v1 = inner_eval(xa.y, cA.z, cA.w);
            float v2 = inner_eval(xa.z, cB.x, cB.y);
            float v3 = inner_eval(xa.w, cB.z, cB.w);
            float v4 = inner_eval(xb.x, cC.x, cC.y);
            float v5 = inner_eval(xb.y, cC.z, cC.w);
            float v6 = inner_eval(xb.z, cD.x, cD.y);
            float v7 = inner_eval(xb.w, cD.z, cD.w);

            union { short8 v; uint32_t u[4]; } af;
            af.u[0] = pack_bf2(v0, v1);
            af.u[1] = pack_bf2(v2, v3);
            af.u[2] = pack_bf2(v4, v5);
            af.u[3] = pack_bf2(v6, v7);

            // --- MFMA sweep over 16 n-tiles (16 independent acc chains) ---
            #pragma unroll
            for (int j = 0; j < 16; ++j)
                acc[j] = __builtin_amdgcn_mfma_f32_16x16x32_bf16(af.v, b[j], acc[j], 0, 0, 0);

            xa = xa_n; xb = xb_n;
        }

        // --- epilogue: fp32 stores; per inst: 4 quad-rows x 64B contiguous segments ---
        float* op = out + (size_t)(mbase + quad * 4) * 256 + mrow;
        #pragma unroll
        for (int j = 0; j < 16; ++j) {
            #pragma unroll
            for (int r = 0; r < 4; ++r)
                op[(size_t)r * 256 + j * 16] = acc[j][r];
        }
    }
}

extern "C" void kernel_launch(void* const* d_in, const int* in_sizes, int n_in,
                              void* d_out, int out_size, void* d_ws, size_t ws_size,
                              hipStream_t stream) {
    const float* x  = (const float*)d_in[0];   // [16,4096,256] fp32
    const float* ic = (const float*)d_in[1];   // [256,5] fp32
    const float* oc = (const float*)d_in[2];   // [256,256] fp32
    char* wb = (char*)d_ws;                    // 128 KB bf16 swizzled copy of W

    conv_w<<<64, 256, 0, stream>>>((const float4*)oc, wb);
    kan_fused<<<256, 512, 0, stream>>>(x, ic, wb, (float*)d_out);
}